// Round 20
// baseline (85.464 us; speedup 1.0000x reference)
//
#include <hip/hip_runtime.h>
#include <math.h>

#define BB 64
#define TT 1024
#define CC 64
#define HH 32
#define KNN 10

typedef float v4f __attribute__((ext_vector_type(4)));
typedef _Float16 f16x8 __attribute__((ext_vector_type(8)));
typedef _Float16 f16x4 __attribute__((ext_vector_type(4)));

__device__ __forceinline__ unsigned umn(unsigned a, unsigned b) { return a < b ? a : b; }
__device__ __forceinline__ unsigned umx(unsigned a, unsigned b) { return a > b ? a : b; }
__device__ __forceinline__ unsigned min3u(unsigned a, unsigned b, unsigned c) {
    unsigned d;
    asm("v_min3_u32 %0, %1, %2, %3" : "=v"(d) : "v"(a), "v"(b), "v"(c));
    return d;
}

// -------- Kernel A: h=x@W1+b1 -> fp16 hi/lo split + hsq=0.5|h|^2*2^20 --------
__global__ __launch_bounds__(256) void h_kernel(
    const float* __restrict__ x, const float* __restrict__ W1,
    const float* __restrict__ b1, _Float16* __restrict__ g16hi,
    _Float16* __restrict__ g16lo, float* __restrict__ hsq)
{
    __shared__ float w1s[CC][HH];
    __shared__ float b1s[HH];
    int tid = threadIdx.x;
    for (int i = tid; i < CC * HH; i += 256) w1s[i >> 5][i & 31] = W1[i];
    if (tid < HH) b1s[tid] = b1[tid];
    __syncthreads();

    int row = blockIdx.x * 256 + tid;
    const float4* xr = (const float4*)(x + (size_t)row * CC);
    float acc[HH];
    #pragma unroll
    for (int j = 0; j < HH; ++j) acc[j] = b1s[j];
    #pragma unroll
    for (int c4 = 0; c4 < CC / 4; ++c4) {
        float4 xv = xr[c4];
        #pragma unroll
        for (int j = 0; j < HH; ++j) {
            acc[j] = fmaf(xv.x, w1s[c4 * 4 + 0][j], acc[j]);
            acc[j] = fmaf(xv.y, w1s[c4 * 4 + 1][j], acc[j]);
            acc[j] = fmaf(xv.z, w1s[c4 * 4 + 2][j], acc[j]);
            acc[j] = fmaf(xv.w, w1s[c4 * 4 + 3][j], acc[j]);
        }
    }
    float s = 0.f;
    #pragma unroll
    for (int j = 0; j < HH; ++j) s = fmaf(acc[j], acc[j], s);

    _Float16* hp = g16hi + (size_t)row * HH;
    _Float16* lp = g16lo + (size_t)row * HH;
    #pragma unroll
    for (int q = 0; q < 4; ++q) {
        f16x8 hi8, lo8;
        #pragma unroll
        for (int e = 0; e < 8; ++e) {
            float v = acc[q * 8 + e];
            _Float16 hh = (_Float16)v;
            hi8[e] = hh;
            lo8[e] = (_Float16)(v - (float)hh);
        }
        *(f16x8*)&hp[q * 8] = hi8;
        *(f16x8*)&lp[q * 8] = lo8;
    }
    hsq[row] = 0.5f * s * 1048576.0f;      // pre-scaled by 2^20 for key math
}

// sorted-pair insert into ascending top-10; explicit v_min3_u32 (29 ops)
#define INSERT_PAIR(kE, kO) do {                                       \
    unsigned lo_ = umn(kE, kO), hi_ = umx(kE, kO);                     \
    bd9 = min3u(bd9, umx(bd8, lo_), umx(bd7, hi_));                    \
    bd8 = min3u(bd8, umx(bd7, lo_), umx(bd6, hi_));                    \
    bd7 = min3u(bd7, umx(bd6, lo_), umx(bd5, hi_));                    \
    bd6 = min3u(bd6, umx(bd5, lo_), umx(bd4, hi_));                    \
    bd5 = min3u(bd5, umx(bd4, lo_), umx(bd3, hi_));                    \
    bd4 = min3u(bd4, umx(bd3, lo_), umx(bd2, hi_));                    \
    bd3 = min3u(bd3, umx(bd2, lo_), umx(bd1, hi_));                    \
    bd2 = min3u(bd2, umx(bd1, lo_), umx(bd0, hi_));                    \
    bd1 = min3u(bd1, umx(bd0, lo_), hi_);                              \
    bd0 = umn(bd0, lo_);                                               \
} while (0)

// one 16-candidate subtile: bias folded into MFMA C (B negated) ->
// acc = (0.5*d2+1) in unscaled units; key = acc*2^20 fixed-point.
#define SUBTILE(U, AHI, ALO) do {                                              \
    const float4 hv = *(const float4*)&hsql[half * 512 + (U) * 16 + kc * 4];   \
    v4f acc;                                                                   \
    acc[0] = fmaf(hv.x, 9.5367431640625e-07f, cinitU);                         \
    acc[1] = fmaf(hv.y, 9.5367431640625e-07f, cinitU);                         \
    acc[2] = fmaf(hv.z, 9.5367431640625e-07f, cinitU);                         \
    acc[3] = fmaf(hv.w, 9.5367431640625e-07f, cinitU);                         \
    acc = __builtin_amdgcn_mfma_f32_16x16x32_f16(AHI, Bnh, acc, 0, 0, 0);      \
    acc = __builtin_amdgcn_mfma_f32_16x16x32_f16(AHI, Bnl, acc, 0, 0, 0);      \
    acc = __builtin_amdgcn_mfma_f32_16x16x32_f16(ALO, Bnh, acc, 0, 0, 0);      \
    int t7b = (U) << 2;                                                        \
    float k0f = acc[0] * 1048576.0f;                                           \
    float k1f = acc[1] * 1048576.0f;                                           \
    float k2f = acc[2] * 1048576.0f;                                           \
    float k3f = acc[3] * 1048576.0f;                                           \
    unsigned p0 = (umn((unsigned)k0f, 0x1FFFFFFu) << 7) | (unsigned)(t7b + 0); \
    unsigned p1 = (umn((unsigned)k1f, 0x1FFFFFFu) << 7) | (unsigned)(t7b + 1); \
    unsigned p2 = (umn((unsigned)k2f, 0x1FFFFFFu) << 7) | (unsigned)(t7b + 2); \
    unsigned p3 = (umn((unsigned)k3f, 0x1FFFFFFu) << 7) | (unsigned)(t7b + 3); \
    p0 = (t7b + 0 == self_t7) ? 0xFFFFFFFFu : p0;                              \
    p1 = (t7b + 1 == self_t7) ? 0xFFFFFFFFu : p1;                              \
    p2 = (t7b + 2 == self_t7) ? 0xFFFFFFFFu : p2;                              \
    p3 = (t7b + 3 == self_t7) ? 0xFFFFFFFFu : p3;                              \
    INSERT_PAIR(p0, p1);                                                       \
    INSERT_PAIR(p2, p3);                                                       \
} while (0)

// ------------- Kernel B: MFMA Gram kNN, candidates direct from L2 ------------
// r19 structure (no hot-loop LDS staging, no hot-loop barriers) + explicit
// v_min3_u32 insert network + bias-in-C MFMA (negated B fragments).
__global__ __launch_bounds__(512, 8) void lap_kernel(
    const _Float16* __restrict__ g16hi, const _Float16* __restrict__ g16lo,
    const float* __restrict__ hsq,
    const float* __restrict__ W2, const float* __restrict__ b2,
    float* __restrict__ out)
{
    __shared__ __align__(16) unsigned char smem[32896];
    auto s_key  = reinterpret_cast<unsigned (*)[64][KNN]>(smem);          // 20 KB
    float* e_wk = reinterpret_cast<float*>(smem + 20480);                 // 2.5 KB
    short* e_id = reinterpret_cast<short*>(smem + 23040);                 // 1.25 KB
    float* e_inv = reinterpret_cast<float*>(smem + 24320);                // 256 B
    float* w2s  = reinterpret_cast<float*>(smem + 24576);                 // 4 KB
    float* b2s  = reinterpret_cast<float*>(smem + 28672);                 // 128 B
    float* hsql = reinterpret_cast<float*>(smem + 28800);                 // 4 KB
    float* a_pool = reinterpret_cast<float*>(smem);                       // 9 KB alias

    int tid  = threadIdx.x;
    int lane = tid & 63;
    int wid  = __builtin_amdgcn_readfirstlane(tid >> 6);   // 0..7

    // bijective XCD/batch swizzle (r12)
    int g   = blockIdx.x;
    int l   = g >> 3;
    int bb  = ((g & 7) << 3) | (l & 7);   // batch
    int rb  = (l >> 3) << 6;              // target row base within batch

    const _Float16* hbh = g16hi + (size_t)bb * TT * HH;
    const _Float16* hbl = g16lo + (size_t)bb * TT * HH;
    const float*    sqb = hsq   + (size_t)bb * TT;

    int gtg  = wid & 3;          // target group 0..3
    int half = wid >> 2;         // candidate half 0..1
    int n    = lane & 15;        // target within group / A-row within subtile
    int kc   = lane >> 4;        // k-chunk 0..3 / candidate row-quad

    // stage hsq to LDS (broadcast source for hv reads) + w2s/b2s
    for (int i = tid; i < TT; i += 512) hsql[i] = sqb[i];
    for (int i = tid; i < HH * HH; i += 512) w2s[i] = W2[i];
    if (tid < HH) b2s[tid] = b2[tid];

    // B fragments, NEGATED (so MFMA computes C - dot)
    int trow = rb + gtg * 16 + n;
    f16x8 Bnh = -*(const f16x8*)&hbh[(size_t)trow * HH + kc * 8];
    f16x8 Bnl = -*(const f16x8*)&hbl[(size_t)trow * HH + kc * 8];
    // cinitU = 0.5*sq_t + 1 (unscaled; sqb is prescaled by 2^20)
    float cinitU = fmaf(sqb[trow], 9.5367431640625e-07f, 1.0f);

    // self candidate: lane sees rows with quad kc of its half
    int s_local = trow - half * 512;
    bool selfok = ((unsigned)s_local < 512u) && (((s_local >> 2) & 3) == kc);
    int self_t7 = selfok ? (((s_local >> 4) << 2) | (s_local & 3)) : -1;

    unsigned bd0 = 0xFFFFFFFFu, bd1 = 0xFFFFFFFFu, bd2 = 0xFFFFFFFFu,
             bd3 = 0xFFFFFFFFu, bd4 = 0xFFFFFFFFu, bd5 = 0xFFFFFFFFu,
             bd6 = 0xFFFFFFFFu, bd7 = 0xFFFFFFFFu, bd8 = 0xFFFFFFFFu,
             bd9 = 0xFFFFFFFFu;

    __syncthreads();   // hsql/w2s ready

    // A-frag address for subtile u: row = half*512 + u*16 + n, k-chunk kc
    const _Float16* abase_h = hbh + ((size_t)(half * 512) + n) * HH + kc * 8;
    const _Float16* abase_l = hbl + ((size_t)(half * 512) + n) * HH + kc * 8;
    #define ALD_H(U) (*(const f16x8*)(abase_h + (size_t)(U) * 16 * HH))
    #define ALD_L(U) (*(const f16x8*)(abase_l + (size_t)(U) * 16 * HH))

    // one-pair lookahead ping-pong; no barriers
    f16x8 A0h = ALD_H(0), A0l = ALD_L(0);
    f16x8 A1h = ALD_H(1), A1l = ALD_L(1);
    for (int u = 0; u < 32; u += 2) {
        int u2 = (u + 2 < 32) ? u + 2 : 31;
        int u3 = (u + 3 < 32) ? u + 3 : 31;
        f16x8 N0h = ALD_H(u2), N0l = ALD_L(u2);
        f16x8 N1h = ALD_H(u3), N1l = ALD_L(u3);
        SUBTILE(u,     A0h, A0l);
        SUBTILE(u + 1, A1h, A1l);
        A0h = N0h; A0l = N0l; A1h = N1h; A1l = N1l;
    }

    // write partial lists: partial id = half*4 + kc; target = gtg*16 + n
    {
        int p  = half * 4 + kc;
        int tr = gtg * 16 + n;
        s_key[p][tr][0] = bd0; s_key[p][tr][1] = bd1;
        s_key[p][tr][2] = bd2; s_key[p][tr][3] = bd3;
        s_key[p][tr][4] = bd4; s_key[p][tr][5] = bd5;
        s_key[p][tr][6] = bd6; s_key[p][tr][7] = bd7;
        s_key[p][tr][8] = bd8; s_key[p][tr][9] = bd9;
    }
    __syncthreads();

    if (wid == 0) {
        // 8-way merge of sorted 10-lists per target (lane = target 0..63)
        unsigned k0 = s_key[0][lane][0], k1 = s_key[1][lane][0];
        unsigned k2 = s_key[2][lane][0], k3 = s_key[3][lane][0];
        unsigned k4 = s_key[4][lane][0], k5 = s_key[5][lane][0];
        unsigned k6 = s_key[6][lane][0], k7 = s_key[7][lane][0];
        int q0=0,q1=0,q2=0,q3=0,q4=0,q5=0,q6=0,q7=0;
        float wsum = 0.f;
        #pragma unroll
        for (int j = 0; j < KNN; ++j) {
            unsigned mn = k0; int c = 0;
            if (k1 < mn) { mn = k1; c = 1; }
            if (k2 < mn) { mn = k2; c = 2; }
            if (k3 < mn) { mn = k3; c = 3; }
            if (k4 < mn) { mn = k4; c = 4; }
            if (k5 < mn) { mn = k5; c = 5; }
            if (k6 < mn) { mn = k6; c = 6; }
            if (k7 < mn) { mn = k7; c = 7; }
            int t7 = (int)(mn & 127u);
            int abs_ = ((c >> 2) << 9) + ((t7 >> 2) << 4) + ((c & 3) << 2)
                       + (t7 & 3);
            float kf = (float)(mn >> 7) * 9.5367431640625e-07f;
            float wk = expf(1.0f - kf);               // exp(-0.5*d2)
            wsum += wk;
            e_id[lane * KNN + j] = (short)abs_;
            e_wk[lane * KNN + j] = wk;
            if      (c == 0) { ++q0; k0 = (q0 < KNN) ? s_key[0][lane][q0] : 0xFFFFFFFFu; }
            else if (c == 1) { ++q1; k1 = (q1 < KNN) ? s_key[1][lane][q1] : 0xFFFFFFFFu; }
            else if (c == 2) { ++q2; k2 = (q2 < KNN) ? s_key[2][lane][q2] : 0xFFFFFFFFu; }
            else if (c == 3) { ++q3; k3 = (q3 < KNN) ? s_key[3][lane][q3] : 0xFFFFFFFFu; }
            else if (c == 4) { ++q4; k4 = (q4 < KNN) ? s_key[4][lane][q4] : 0xFFFFFFFFu; }
            else if (c == 5) { ++q5; k5 = (q5 < KNN) ? s_key[5][lane][q5] : 0xFFFFFFFFu; }
            else if (c == 6) { ++q6; k6 = (q6 < KNN) ? s_key[6][lane][q6] : 0xFFFFFFFFu; }
            else             { ++q7; k7 = (q7 < KNN) ? s_key[7][lane][q7] : 0xFFFFFFFFu; }
        }
        e_inv[lane] = 1.0f / (wsum + 1e-8f);
    }
    __syncthreads();

    // gather + smooth + tanh; h~ = hi+lo reconstruction (err ~2^-22)
    {
        int r  = tid >> 3;             // 0..63
        int g2 = (tid & 7) << 2;       // dim base 0,4,...,28
        float ax = 0.f, ay = 0.f, az = 0.f, aw = 0.f;
        #pragma unroll
        for (int k = 0; k < KNN; ++k) {
            int idx  = e_id[r * KNN + k];
            float wk = e_wk[r * KNN + k];
            f16x4 nh = *(const f16x4*)&hbh[(size_t)idx * HH + g2];
            f16x4 nl = *(const f16x4*)&hbl[(size_t)idx * HH + g2];
            ax = fmaf(wk, (float)nh[0] + (float)nl[0], ax);
            ay = fmaf(wk, (float)nh[1] + (float)nl[1], ay);
            az = fmaf(wk, (float)nh[2] + (float)nl[2], az);
            aw = fmaf(wk, (float)nh[3] + (float)nl[3], aw);
        }
        float inv = e_inv[r];
        f16x4 th = *(const f16x4*)&hbh[(size_t)(rb + r) * HH + g2];
        f16x4 tl = *(const f16x4*)&hbl[(size_t)(rb + r) * HH + g2];
        float4 av;
        av.x = tanhf(fmaf(-ax, inv, (float)th[0] + (float)tl[0]));
        av.y = tanhf(fmaf(-ay, inv, (float)th[1] + (float)tl[1]));
        av.z = tanhf(fmaf(-az, inv, (float)th[2] + (float)tl[2]));
        av.w = tanhf(fmaf(-aw, inv, (float)th[3] + (float)tl[3]));
        *(float4*)&a_pool[r * 36 + g2] = av;
    }
    __syncthreads();

    // out = a @ W2 + b2 ; thread -> (row r, 4 consecutive output dims)
    int r   = tid >> 3;
    int c0_ = (tid & 7) << 2;
    float o[4];
    #pragma unroll
    for (int u = 0; u < 4; ++u) o[u] = b2s[c0_ + u];
    #pragma unroll
    for (int j = 0; j < HH; ++j) {
        float av = a_pool[r * 36 + j];
        #pragma unroll
        for (int u = 0; u < 4; ++u) o[u] = fmaf(av, w2s[j * HH + c0_ + u], o[u]);
    }
    float* op = out + ((size_t)bb * TT + rb + r) * HH + c0_;
    float4 o1 = { o[0], o[1], o[2], o[3] };
    *((float4*)op) = o1;
}

extern "C" void kernel_launch(void* const* d_in, const int* in_sizes, int n_in,
                              void* d_out, int out_size, void* d_ws, size_t ws_size,
                              hipStream_t stream) {
    const float* x  = (const float*)d_in[0];
    const float* W1 = (const float*)d_in[1];
    const float* b1 = (const float*)d_in[2];
    const float* W2 = (const float*)d_in[3];
    const float* b2 = (const float*)d_in[4];
    float* outp = (float*)d_out;

    // workspace: g16hi (4.19MB) | g16lo (4.19MB) | hsq (0.26MB) = 8.65MB
    _Float16* g16hi = (_Float16*)d_ws;
    _Float16* g16lo = g16hi + (size_t)BB * TT * HH;
    float*    hsq   = (float*)(g16lo + (size_t)BB * TT * HH);

    h_kernel<<<(BB * TT) / 256, 256, 0, stream>>>(x, W1, b1, g16hi, g16lo, hsq);
    lap_kernel<<<BB * (TT / 64), 512, 0, stream>>>(g16hi, g16lo, hsq, W2, b2, outp);
}

// Round 21
// 76.424 us; speedup vs baseline: 1.1183x; 1.1183x over previous
//
#include <hip/hip_runtime.h>
#include <math.h>

#define BB 64
#define TT 1024
#define CC 64
#define HH 32
#define KNN 10

typedef float v4f __attribute__((ext_vector_type(4)));
typedef _Float16 f16x8 __attribute__((ext_vector_type(8)));
typedef _Float16 f16x4 __attribute__((ext_vector_type(4)));

__device__ __forceinline__ unsigned umn(unsigned a, unsigned b) { return a < b ? a : b; }
__device__ __forceinline__ unsigned umx(unsigned a, unsigned b) { return a > b ? a : b; }

// -------- Kernel A: h=x@W1+b1 -> fp16 hi/lo split + hsq=0.5|h|^2*2^20 --------
__global__ __launch_bounds__(256) void h_kernel(
    const float* __restrict__ x, const float* __restrict__ W1,
    const float* __restrict__ b1, _Float16* __restrict__ g16hi,
    _Float16* __restrict__ g16lo, float* __restrict__ hsq)
{
    __shared__ float w1s[CC][HH];
    __shared__ float b1s[HH];
    int tid = threadIdx.x;
    for (int i = tid; i < CC * HH; i += 256) w1s[i >> 5][i & 31] = W1[i];
    if (tid < HH) b1s[tid] = b1[tid];
    __syncthreads();

    int row = blockIdx.x * 256 + tid;
    const float4* xr = (const float4*)(x + (size_t)row * CC);
    float acc[HH];
    #pragma unroll
    for (int j = 0; j < HH; ++j) acc[j] = b1s[j];
    #pragma unroll
    for (int c4 = 0; c4 < CC / 4; ++c4) {
        float4 xv = xr[c4];
        #pragma unroll
        for (int j = 0; j < HH; ++j) {
            acc[j] = fmaf(xv.x, w1s[c4 * 4 + 0][j], acc[j]);
            acc[j] = fmaf(xv.y, w1s[c4 * 4 + 1][j], acc[j]);
            acc[j] = fmaf(xv.z, w1s[c4 * 4 + 2][j], acc[j]);
            acc[j] = fmaf(xv.w, w1s[c4 * 4 + 3][j], acc[j]);
        }
    }
    float s = 0.f;
    #pragma unroll
    for (int j = 0; j < HH; ++j) s = fmaf(acc[j], acc[j], s);

    _Float16* hp = g16hi + (size_t)row * HH;
    _Float16* lp = g16lo + (size_t)row * HH;
    #pragma unroll
    for (int q = 0; q < 4; ++q) {
        f16x8 hi8, lo8;
        #pragma unroll
        for (int e = 0; e < 8; ++e) {
            float v = acc[q * 8 + e];
            _Float16 hh = (_Float16)v;
            hi8[e] = hh;
            lo8[e] = (_Float16)(v - (float)hh);
        }
        *(f16x8*)&hp[q * 8] = hi8;
        *(f16x8*)&lp[q * 8] = lo8;
    }
    hsq[row] = 0.5f * s * 1048576.0f;      // pre-scaled by 2^20 for key math
}

#define INSERT_PAIR(kE, kO) do {                                       \
    unsigned lo_ = umn(kE, kO), hi_ = umx(kE, kO);                     \
    bd9 = umn(umn(bd9, umx(bd8, lo_)), umx(bd7, hi_));                 \
    bd8 = umn(umn(bd8, umx(bd7, lo_)), umx(bd6, hi_));                 \
    bd7 = umn(umn(bd7, umx(bd6, lo_)), umx(bd5, hi_));                 \
    bd6 = umn(umn(bd6, umx(bd5, lo_)), umx(bd4, hi_));                 \
    bd5 = umn(umn(bd5, umx(bd4, lo_)), umx(bd3, hi_));                 \
    bd4 = umn(umn(bd4, umx(bd3, lo_)), umx(bd2, hi_));                 \
    bd3 = umn(umn(bd3, umx(bd2, lo_)), umx(bd1, hi_));                 \
    bd2 = umn(umn(bd2, umx(bd1, lo_)), umx(bd0, hi_));                 \
    bd1 = umn(umn(bd1, umx(bd0, lo_)), hi_);                           \
    bd0 = umn(bd0, lo_);                                               \
} while (0)

// compute keys+insert for one 16-candidate subtile u (A-frags in regs)
#define SUBTILE(U, AHI, ALO) do {                                              \
    v4f acc = { 0.f, 0.f, 0.f, 0.f };                                          \
    acc = __builtin_amdgcn_mfma_f32_16x16x32_f16(AHI, Bhi, acc, 0, 0, 0);      \
    acc = __builtin_amdgcn_mfma_f32_16x16x32_f16(AHI, Blo, acc, 0, 0, 0);      \
    acc = __builtin_amdgcn_mfma_f32_16x16x32_f16(ALO, Bhi, acc, 0, 0, 0);      \
    const float4 hv = *(const float4*)&hsql[half * 512 + (U) * 16 + kc * 4];   \
    int t7b = (U) << 2;                                                        \
    float k0f = fmaf(acc[0], -1048576.0f, cinit20 + hv.x);                     \
    float k1f = fmaf(acc[1], -1048576.0f, cinit20 + hv.y);                     \
    float k2f = fmaf(acc[2], -1048576.0f, cinit20 + hv.z);                     \
    float k3f = fmaf(acc[3], -1048576.0f, cinit20 + hv.w);                     \
    unsigned p0 = (umn((unsigned)k0f, 0x1FFFFFFu) << 7) | (unsigned)(t7b + 0); \
    unsigned p1 = (umn((unsigned)k1f, 0x1FFFFFFu) << 7) | (unsigned)(t7b + 1); \
    unsigned p2 = (umn((unsigned)k2f, 0x1FFFFFFu) << 7) | (unsigned)(t7b + 2); \
    unsigned p3 = (umn((unsigned)k3f, 0x1FFFFFFu) << 7) | (unsigned)(t7b + 3); \
    p0 = (t7b + 0 == self_t7) ? 0xFFFFFFFFu : p0;                              \
    p1 = (t7b + 1 == self_t7) ? 0xFFFFFFFFu : p1;                              \
    p2 = (t7b + 2 == self_t7) ? 0xFFFFFFFFu : p2;                              \
    p3 = (t7b + 3 == self_t7) ? 0xFFFFFFFFu : p3;                              \
    INSERT_PAIR(p0, p1);                                                       \
    INSERT_PAIR(p2, p3);                                                       \
} while (0)

// ------------- Kernel B: MFMA Gram kNN, candidates direct from L2 ------------
// r19 EXACTLY, except __launch_bounds__(512, 4): the (512,8) floor capped the
// allocator at 64 VGPRs and it chose 32 -> live set (16 lookahead A-frags +
// B-frags + bd[10]) overflowed into AGPRs, and every bd access paid
// v_accvgpr_read/write (the missing ~2.7x VALU ops). 128-VGPR budget removes
// the AGPR shuffle; occupancy 57->~50% is cheap since we're VALU-issue-bound.
__global__ __launch_bounds__(512, 4) void lap_kernel(
    const _Float16* __restrict__ g16hi, const _Float16* __restrict__ g16lo,
    const float* __restrict__ hsq,
    const float* __restrict__ W2, const float* __restrict__ b2,
    float* __restrict__ out)
{
    __shared__ __align__(16) unsigned char smem[32896];
    auto s_key  = reinterpret_cast<unsigned (*)[64][KNN]>(smem);          // 20 KB
    float* e_wk = reinterpret_cast<float*>(smem + 20480);                 // 2.5 KB
    short* e_id = reinterpret_cast<short*>(smem + 23040);                 // 1.25 KB
    float* e_inv = reinterpret_cast<float*>(smem + 24320);                // 256 B
    float* w2s  = reinterpret_cast<float*>(smem + 24576);                 // 4 KB
    float* b2s  = reinterpret_cast<float*>(smem + 28672);                 // 128 B
    float* hsql = reinterpret_cast<float*>(smem + 28800);                 // 4 KB
    float* a_pool = reinterpret_cast<float*>(smem);                       // 9 KB alias

    int tid  = threadIdx.x;
    int lane = tid & 63;
    int wid  = __builtin_amdgcn_readfirstlane(tid >> 6);   // 0..7

    // bijective XCD/batch swizzle (r12)
    int g   = blockIdx.x;
    int l   = g >> 3;
    int bb  = ((g & 7) << 3) | (l & 7);   // batch
    int rb  = (l >> 3) << 6;              // target row base within batch

    const _Float16* hbh = g16hi + (size_t)bb * TT * HH;
    const _Float16* hbl = g16lo + (size_t)bb * TT * HH;
    const float*    sqb = hsq   + (size_t)bb * TT;

    int gtg  = wid & 3;          // target group 0..3
    int half = wid >> 2;         // candidate half 0..1
    int n    = lane & 15;        // target within group / A-row within subtile
    int kc   = lane >> 4;        // k-chunk 0..3 / candidate row-quad

    // stage hsq to LDS (broadcast source for hv reads) + w2s/b2s
    for (int i = tid; i < TT; i += 512) hsql[i] = sqb[i];
    for (int i = tid; i < HH * HH; i += 512) w2s[i] = W2[i];
    if (tid < HH) b2s[tid] = b2[tid];

    // B fragments: direct fp16 loads (pre-split in kernel A)
    int trow = rb + gtg * 16 + n;
    f16x8 Bhi = *(const f16x8*)&hbh[(size_t)trow * HH + kc * 8];
    f16x8 Blo = *(const f16x8*)&hbl[(size_t)trow * HH + kc * 8];
    float cinit20 = sqb[trow] + 1048576.0f;   // (0.5 sq_t + 1) * 2^20

    // self candidate: lane sees rows with quad kc of its half
    int s_local = trow - half * 512;
    bool selfok = ((unsigned)s_local < 512u) && (((s_local >> 2) & 3) == kc);
    int self_t7 = selfok ? (((s_local >> 4) << 2) | (s_local & 3)) : -1;

    unsigned bd0 = 0xFFFFFFFFu, bd1 = 0xFFFFFFFFu, bd2 = 0xFFFFFFFFu,
             bd3 = 0xFFFFFFFFu, bd4 = 0xFFFFFFFFu, bd5 = 0xFFFFFFFFu,
             bd6 = 0xFFFFFFFFu, bd7 = 0xFFFFFFFFu, bd8 = 0xFFFFFFFFu,
             bd9 = 0xFFFFFFFFu;

    __syncthreads();   // hsql/w2s ready

    // A-frag address for subtile u: row = half*512 + u*16 + n, k-chunk kc
    const _Float16* abase_h = hbh + ((size_t)(half * 512) + n) * HH + kc * 8;
    const _Float16* abase_l = hbl + ((size_t)(half * 512) + n) * HH + kc * 8;
    #define ALD_H(U) (*(const f16x8*)(abase_h + (size_t)(U) * 16 * HH))
    #define ALD_L(U) (*(const f16x8*)(abase_l + (size_t)(U) * 16 * HH))

    // one-pair lookahead ping-pong; no barriers
    f16x8 A0h = ALD_H(0), A0l = ALD_L(0);
    f16x8 A1h = ALD_H(1), A1l = ALD_L(1);
    for (int u = 0; u < 32; u += 2) {
        int u2 = (u + 2 < 32) ? u + 2 : 31;
        int u3 = (u + 3 < 32) ? u + 3 : 31;
        f16x8 N0h = ALD_H(u2), N0l = ALD_L(u2);
        f16x8 N1h = ALD_H(u3), N1l = ALD_L(u3);
        SUBTILE(u,     A0h, A0l);
        SUBTILE(u + 1, A1h, A1l);
        A0h = N0h; A0l = N0l; A1h = N1h; A1l = N1l;
    }

    // write partial lists: partial id = half*4 + kc; target = gtg*16 + n
    {
        int p  = half * 4 + kc;
        int tr = gtg * 16 + n;
        s_key[p][tr][0] = bd0; s_key[p][tr][1] = bd1;
        s_key[p][tr][2] = bd2; s_key[p][tr][3] = bd3;
        s_key[p][tr][4] = bd4; s_key[p][tr][5] = bd5;
        s_key[p][tr][6] = bd6; s_key[p][tr][7] = bd7;
        s_key[p][tr][8] = bd8; s_key[p][tr][9] = bd9;
    }
    __syncthreads();

    if (wid == 0) {
        // 8-way merge of sorted 10-lists per target (lane = target 0..63)
        unsigned k0 = s_key[0][lane][0], k1 = s_key[1][lane][0];
        unsigned k2 = s_key[2][lane][0], k3 = s_key[3][lane][0];
        unsigned k4 = s_key[4][lane][0], k5 = s_key[5][lane][0];
        unsigned k6 = s_key[6][lane][0], k7 = s_key[7][lane][0];
        int q0=0,q1=0,q2=0,q3=0,q4=0,q5=0,q6=0,q7=0;
        float wsum = 0.f;
        #pragma unroll
        for (int j = 0; j < KNN; ++j) {
            unsigned mn = k0; int c = 0;
            if (k1 < mn) { mn = k1; c = 1; }
            if (k2 < mn) { mn = k2; c = 2; }
            if (k3 < mn) { mn = k3; c = 3; }
            if (k4 < mn) { mn = k4; c = 4; }
            if (k5 < mn) { mn = k5; c = 5; }
            if (k6 < mn) { mn = k6; c = 6; }
            if (k7 < mn) { mn = k7; c = 7; }
            int t7 = (int)(mn & 127u);
            int abs_ = ((c >> 2) << 9) + ((t7 >> 2) << 4) + ((c & 3) << 2)
                       + (t7 & 3);
            float kf = (float)(mn >> 7) * 9.5367431640625e-07f;
            float wk = expf(1.0f - kf);               // exp(-0.5*d2)
            wsum += wk;
            e_id[lane * KNN + j] = (short)abs_;
            e_wk[lane * KNN + j] = wk;
            if      (c == 0) { ++q0; k0 = (q0 < KNN) ? s_key[0][lane][q0] : 0xFFFFFFFFu; }
            else if (c == 1) { ++q1; k1 = (q1 < KNN) ? s_key[1][lane][q1] : 0xFFFFFFFFu; }
            else if (c == 2) { ++q2; k2 = (q2 < KNN) ? s_key[2][lane][q2] : 0xFFFFFFFFu; }
            else if (c == 3) { ++q3; k3 = (q3 < KNN) ? s_key[3][lane][q3] : 0xFFFFFFFFu; }
            else if (c == 4) { ++q4; k4 = (q4 < KNN) ? s_key[4][lane][q4] : 0xFFFFFFFFu; }
            else if (c == 5) { ++q5; k5 = (q5 < KNN) ? s_key[5][lane][q5] : 0xFFFFFFFFu; }
            else if (c == 6) { ++q6; k6 = (q6 < KNN) ? s_key[6][lane][q6] : 0xFFFFFFFFu; }
            else             { ++q7; k7 = (q7 < KNN) ? s_key[7][lane][q7] : 0xFFFFFFFFu; }
        }
        e_inv[lane] = 1.0f / (wsum + 1e-8f);
    }
    __syncthreads();

    // gather + smooth + tanh; h~ = hi+lo reconstruction (err ~2^-22)
    {
        int r  = tid >> 3;             // 0..63
        int g2 = (tid & 7) << 2;       // dim base 0,4,...,28
        float ax = 0.f, ay = 0.f, az = 0.f, aw = 0.f;
        #pragma unroll
        for (int k = 0; k < KNN; ++k) {
            int idx  = e_id[r * KNN + k];
            float wk = e_wk[r * KNN + k];
            f16x4 nh = *(const f16x4*)&hbh[(size_t)idx * HH + g2];
            f16x4 nl = *(const f16x4*)&hbl[(size_t)idx * HH + g2];
            ax = fmaf(wk, (float)nh[0] + (float)nl[0], ax);
            ay = fmaf(wk, (float)nh[1] + (float)nl[1], ay);
            az = fmaf(wk, (float)nh[2] + (float)nl[2], az);
            aw = fmaf(wk, (float)nh[3] + (float)nl[3], aw);
        }
        float inv = e_inv[r];
        f16x4 th = *(const f16x4*)&hbh[(size_t)(rb + r) * HH + g2];
        f16x4 tl = *(const f16x4*)&hbl[(size_t)(rb + r) * HH + g2];
        float4 av;
        av.x = tanhf(fmaf(-ax, inv, (float)th[0] + (float)tl[0]));
        av.y = tanhf(fmaf(-ay, inv, (float)th[1] + (float)tl[1]));
        av.z = tanhf(fmaf(-az, inv, (float)th[2] + (float)tl[2]));
        av.w = tanhf(fmaf(-aw, inv, (float)th[3] + (float)tl[3]));
        *(float4*)&a_pool[r * 36 + g2] = av;
    }
    __syncthreads();

    // out = a @ W2 + b2 ; thread -> (row r, 4 consecutive output dims)
    int r   = tid >> 3;
    int c0_ = (tid & 7) << 2;
    float o[4];
    #pragma unroll
    for (int u = 0; u < 4; ++u) o[u] = b2s[c0_ + u];
    #pragma unroll
    for (int j = 0; j < HH; ++j) {
        float av = a_pool[r * 36 + j];
        #pragma unroll
        for (int u = 0; u < 4; ++u) o[u] = fmaf(av, w2s[j * HH + c0_ + u], o[u]);
    }
    float* op = out + ((size_t)bb * TT + rb + r) * HH + c0_;
    float4 o1 = { o[0], o[1], o[2], o[3] };
    *((float4*)op) = o1;
}

extern "C" void kernel_launch(void* const* d_in, const int* in_sizes, int n_in,
                              void* d_out, int out_size, void* d_ws, size_t ws_size,
                              hipStream_t stream) {
    const float* x  = (const float*)d_in[0];
    const float* W1 = (const float*)d_in[1];
    const float* b1 = (const float*)d_in[2];
    const float* W2 = (const float*)d_in[3];
    const float* b2 = (const float*)d_in[4];
    float* outp = (float*)d_out;

    // workspace: g16hi (4.19MB) | g16lo (4.19MB) | hsq (0.26MB) = 8.65MB
    _Float16* g16hi = (_Float16*)d_ws;
    _Float16* g16lo = g16hi + (size_t)BB * TT * HH;
    float*    hsq   = (float*)(g16lo + (size_t)BB * TT * HH);

    h_kernel<<<(BB * TT) / 256, 256, 0, stream>>>(x, W1, b1, g16hi, g16lo, hsq);
    lap_kernel<<<BB * (TT / 64), 512, 0, stream>>>(g16hi, g16lo, hsq, W2, b2, outp);
}